// Round 1
// baseline (1527.773 us; speedup 1.0000x reference)
//
#include <hip/hip_runtime.h>
#include <hip/hip_cooperative_groups.h>

namespace cg = cooperative_groups;

// ToDenseBEVConvolution R12 — ONE cooperative dispatch (was 6 graph nodes).
// R10/R11 established ~12us per dispatch boundary and dense at fill-rate;
// remaining addressable cost is boundaries. Phases inside one kernel:
//  A0: zero head+gcnt (grid-stride; replaces hipMemsetAsync node)
//  A1: bucket sort by k-bin (identical logic to R11 bev_sort, grid-strided)
//  B : binned matmul, kern[bin] staged in LDS; contiguous virtual-chunk range
//      per block so same-bin chunks reuse the staged LDS; empty bin tails
//      skipped in O(1) (jump to next bin).
//  C : dense output; block = (b,x): head row staged to LDS ONCE (R11 re-read
//      it per-o from L2), 4 waves split the 128 channels, D4's chain-fold is
//      inlined as a per-cell walk (96% singletons). f reads become block-local
//      (~39 rows * 512B per block -> L1/L2 resident).
// grid = min(batch*BEVH, occupancy*CUs) = 1024 @ 4 blocks/CU (LDS 32.9KB).

#define CIN    64
#define COUT   128
#define BEVH   512
#define BEVW   512
#define HW     (BEVH * BEVW)     // 2^18
#define NBINS  16
#define PTS_PER_WAVE  8
#define PTS_PER_BLOCK 32

__global__ __launch_bounds__(256, 4) void bev_fused(
    const int*   __restrict__ coords,   // [N,4]
    const float* __restrict__ feats,    // [N,64]
    const float* __restrict__ kern,     // [16,64,128]
    const int*   __restrict__ stride_p,
    int*         __restrict__ gcnt,     // [16] (zeroed in A0)
    int*         __restrict__ sorted,   // [16*N]
    float*       __restrict__ f,        // [N,128]
    int*         __restrict__ head,     // [ncells] (zeroed in A0), stores pt+1
    int*         __restrict__ nxt,      // [N]; 0 = end-of-chain
    float*       __restrict__ out,      // [B,128,512,512]
    int n, int chunks_per_bin, int ncells, int batch)
{
    __shared__ float lk[CIN * COUT];          // 32 KB; phase C reuses as int[]
    __shared__ int hist[NBINS], base[NBINS];

    const int tid  = threadIdx.x;
    const int wave = tid >> 6;
    const int lane = tid & 63;
    const int stride = stride_p[0];
    cg::grid_group grid = cg::this_grid();

    // ---------------- A0: zero head+gcnt (contiguous in ws -> one loop)
    {
        const int gt = blockIdx.x * 256 + tid;
        const int gs = gridDim.x * 256;
        for (int i = gt; i < ncells + NBINS; i += gs) head[i] = 0;
    }
    grid.sync();

    // ---------------- A1: bucket point indices by k-bin
    {
        const int nvb = (n + 255) / 256;
        for (int vb = blockIdx.x; vb < nvb; vb += gridDim.x) {
            if (tid < NBINS) hist[tid] = 0;
            __syncthreads();
            const int i = vb * 256 + tid;
            int k = 0, rank = 0;
            if (i < n) {
                k = coords[i * 4 + 1] / stride;
                rank = atomicAdd(&hist[k], 1);        // LDS atomic: local rank
            }
            __syncthreads();
            if (tid < NBINS)
                base[tid] = hist[tid] ? atomicAdd(&gcnt[tid], hist[tid]) : 0;
            __syncthreads();
            if (i < n) sorted[k * n + base[k] + rank] = i;
            __syncthreads();                          // hist reuse next vb
        }
    }
    grid.sync();

    // ---------------- B: binned matmul, kern[bin] in LDS
    {
        const int total_vc = NBINS * chunks_per_bin;
        const int per_blk  = (total_vc + gridDim.x - 1) / gridDim.x;
        int vc = blockIdx.x * per_blk;
        const int vc_end = (vc + per_blk < total_vc) ? vc + per_blk : total_vc;
        int staged_bin = -1;
        while (vc < vc_end) {                         // all control flow here is
            const int bin   = vc / chunks_per_bin;    // block-uniform (scalar)
            const int chunk = vc - bin * chunks_per_bin;
            const int cnt   = gcnt[bin];
            if (chunk * PTS_PER_BLOCK >= cnt) {       // bin tail empty: skip bin
                vc = (bin + 1) * chunks_per_bin;
                continue;
            }
            if (bin != staged_bin) {
                __syncthreads();                      // prior lk use done
                const float4* src = (const float4*)(kern + (size_t)bin * CIN * COUT);
                float4* dst = (float4*)lk;
#pragma unroll
                for (int j = 0; j < 8; ++j)
                    dst[j * 256 + tid] = src[j * 256 + tid];
                __syncthreads();
                staged_bin = bin;
            }
            const int r0 = chunk * PTS_PER_BLOCK + wave * PTS_PER_WAVE;
            const int navail = cnt - r0;
            if (navail > 0) {                         // per-wave guard (no return!)
                const int np = navail < PTS_PER_WAVE ? navail : PTS_PER_WAVE;
                int pts[PTS_PER_WAVE];
#pragma unroll
                for (int p = 0; p < PTS_PER_WAVE; ++p) {
                    const int rr = (p < np) ? (r0 + p) : r0;   // pad tail w/ p0
                    pts[p] = __builtin_amdgcn_readfirstlane(sorted[bin * n + rr]);
                }
                float ax[PTS_PER_WAVE], ay[PTS_PER_WAVE];
#pragma unroll
                for (int p = 0; p < PTS_PER_WAVE; ++p) { ax[p] = 0.f; ay[p] = 0.f; }
#pragma unroll
                for (int c = 0; c < CIN; ++c) {
                    const float2 kv = *(const float2*)&lk[c * COUT + 2 * lane];
#pragma unroll
                    for (int p = 0; p < PTS_PER_WAVE; ++p) {
                        const float fv = feats[(size_t)pts[p] * CIN + c]; // s_load
                        ax[p] = fmaf(fv, kv.x, ax[p]);
                        ay[p] = fmaf(fv, kv.y, ay[p]);
                    }
                }
#pragma unroll
                for (int p = 0; p < PTS_PER_WAVE; ++p)
                    if (p < np)
                        *(float2*)(f + (size_t)pts[p] * COUT + 2 * lane) =
                            make_float2(ax[p], ay[p]);
                if (lane == 0) {
                    for (int p = 0; p < np; ++p) {
                        const int pt = pts[p];
                        const int cx = coords[pt * 4 + 0];
                        const int cz = coords[pt * 4 + 2];
                        const int cb = coords[pt * 4 + 3];
                        const int cell = (cb << 18) + ((cx / stride) << 9) + (cz / stride);
                        const int old = atomicExch(&head[cell], pt + 1); // lock-free push
                        nxt[pt] = old;                                   // 0 = end
                    }
                }
            }
            ++vc;
        }
    }
    grid.sync();

    // ---------------- C: dense output; block = (b,x); head row in LDS;
    //                    D4 chain-fold inlined as per-cell walk
    {
        int* lh = (int*)lk;                           // reuse 32KB LDS (need 2KB)
        const int nbx = batch * BEVH;
        for (int bx = blockIdx.x; bx < nbx; bx += gridDim.x) {
            const int b = bx >> 9;
            const int x = bx & (BEVH - 1);
            __syncthreads();                          // prior lh reads done
            {
                const int* hrow = head + (b << 18) + (x << 9);
                for (int i = tid; i < BEVW; i += 256) lh[i] = hrow[i];
            }
            __syncthreads();
            for (int o = wave; o < COUT; o += 4) {    // 4 waves split channels
                float* orow = out + (((size_t)(b * COUT + o)) << 18) + ((size_t)x << 9);
#pragma unroll
                for (int h = 0; h < 2; ++h) {
                    const int z = h * 256 + lane * 4;
                    const int4 h4 = *(const int4*)&lh[z];     // LDS, conflict-free
                    float4 v = make_float4(0.f, 0.f, 0.f, 0.f);
                    int p;
                    p = h4.x; while (p) { v.x += f[(size_t)(p - 1) * COUT + o]; p = nxt[p - 1]; }
                    p = h4.y; while (p) { v.y += f[(size_t)(p - 1) * COUT + o]; p = nxt[p - 1]; }
                    p = h4.z; while (p) { v.z += f[(size_t)(p - 1) * COUT + o]; p = nxt[p - 1]; }
                    p = h4.w; while (p) { v.w += f[(size_t)(p - 1) * COUT + o]; p = nxt[p - 1]; }
                    *(float4*)(orow + z) = v;                 // coalesced 1KB/wave
                }
            }
        }
    }
}

// ------------------------------------------------------------------- launch
extern "C" void kernel_launch(void* const* d_in, const int* in_sizes, int n_in,
                              void* d_out, int out_size, void* d_ws, size_t ws_size,
                              hipStream_t stream) {
    const int*   coords   = (const int*)d_in[0];
    const float* feats    = (const float*)d_in[1];
    const float* kern     = (const float*)d_in[2];
    const int*   stride_p = (const int*)d_in[3];
    float* out = (float*)d_out;

    const int n      = in_sizes[0] / 4;          // coords is [N,4] (element count)
    const int ncells = out_size / COUT;          // B*H*W
    const int batch  = out_size / (COUT * HW);
    const int chunks_per_bin = (n + PTS_PER_BLOCK - 1) / PTS_PER_BLOCK;

    // Workspace: f | head | gcnt | nxt | sorted  (head+gcnt contiguous: A0 zero)
    size_t off = 0;
    float* f    = (float*)((char*)d_ws + off);   off += (size_t)n * COUT * sizeof(float);
    int* head   = (int*)((char*)d_ws + off);     off += (size_t)ncells * sizeof(int);
    int* gcnt   = (int*)((char*)d_ws + off);     off += NBINS * sizeof(int);
    int* nxt    = (int*)((char*)d_ws + off);     off += (size_t)n * sizeof(int);
    int* sorted = (int*)((char*)d_ws + off);     off += (size_t)NBINS * n * sizeof(int);

    // One-time co-residency capacity (host-side queries only; no stream ops)
    static int grid_max = 0;
    if (grid_max == 0) {
        int nb = 0;
        (void)hipOccupancyMaxActiveBlocksPerMultiprocessor(&nb, bev_fused, 256, 0);
        int ncu = 0;
        hipDeviceProp_t prop;
        if (hipGetDeviceProperties(&prop, 0) == hipSuccess)
            ncu = prop.multiProcessorCount;
        if (nb  <= 0) nb  = 1;
        if (ncu <= 0) ncu = 256;
        grid_max = nb * ncu;
    }
    int grid = batch * BEVH;                     // 1024: one block per (b,x)
    if (grid > grid_max) grid = grid_max;        // all phases grid-stride safely

    void* kargs[] = {
        (void*)&coords, (void*)&feats, (void*)&kern, (void*)&stride_p,
        (void*)&gcnt, (void*)&sorted, (void*)&f, (void*)&head, (void*)&nxt,
        (void*)&out, (void*)&n, (void*)&chunks_per_bin, (void*)&ncells,
        (void*)&batch
    };
    (void)hipLaunchCooperativeKernel((void*)bev_fused, dim3(grid), dim3(256),
                                     kargs, 0, stream);
}

// Round 2
// 450.901 us; speedup vs baseline: 3.3883x; 3.3883x over previous
//
#include <hip/hip_runtime.h>

// ToDenseBEVConvolution R13 — back to multi-dispatch (R12 cooperative fusion
// FALSIFIED: 1024-block co-residency destroyed TLP -> 898us latency-bound).
// Keep R11's proven kernels + massive grids, but cut 5 nodes -> 3:
//  K1 bev_sort:  zeroes head inline (memset node deleted) and replaces the
//                global gcnt atomic with deterministic per-block histograms
//                (blkhist) + block-segmented sorted layout (no init needed).
//  K2 bev_point: exact-chunk grid (1266 vs 20000); each block rebuilds bin
//                totals + per-block prefix from blkhist in LDS (~10KB, ~1us),
//                binary-searches its 8 ranks, then R11's LDS-kernel matmul +
//                chain push (head=pt+1 atomicExch, nxt[pt]=old, 0=end).
//  K3 bev_dense_row: R11 fill-rate dense (32768 blocks, int4 head row, float4
//                stores) with D4's chain-fold inlined: 4 f-loads + 4 nxt-loads
//                issued in parallel (1 latency level for ~96% singletons),
//                rare >=2 chains in an exec-masked loop (accum node deleted).
// Per-cell sum order = owner first then chain = identical to R11 (absmax 0.0).
// NOTE: assumes nblk=(N+255)/256 <= 256 (N <= 65536; harness N=40000).

#define CIN    64
#define COUT   128
#define BEVH   512
#define BEVW   512
#define HW     (BEVH * BEVW)     // 2^18
#define NBINS  16
#define PTS_PER_WAVE  8
#define PTS_PER_BLOCK 32

// ---------------- K1: zero head + deterministic per-block bucket (no atomics
//                  on global counters; blkhist/sorted fully written)
__global__ __launch_bounds__(256) void bev_sort(
    const int* __restrict__ coords,   // [N,4]
    const int* __restrict__ stride_p,
    int*       __restrict__ head,     // [ncells] -> zeroed here
    int*       __restrict__ blkhist,  // [nblk,16]
    int*       __restrict__ sorted,   // [16, nblk*256] block-segmented
    int n, int nblk, int scap, int ncells)
{
    __shared__ int hist[NBINS];
    const int tid = threadIdx.x;
    const int vb  = blockIdx.x;

    // zero head (2MB over nblk*256 threads, int4 grid-stride)
    {
        int4* h4 = (int4*)head;
        const int tot4 = ncells >> 2;
        const int zero_stride = nblk * 256;
        for (int i = vb * 256 + tid; i < tot4; i += zero_stride)
            h4[i] = make_int4(0, 0, 0, 0);
    }

    if (tid < NBINS) hist[tid] = 0;
    __syncthreads();

    const int i = vb * 256 + tid;
    int k = 0, rank = 0;
    if (i < n) {
        k = coords[i * 4 + 1] / stride_p[0];
        rank = atomicAdd(&hist[k], 1);        // LDS atomic: block-local rank
    }
    __syncthreads();
    if (i < n)
        sorted[k * scap + vb * 256 + rank] = i;
    if (tid < NBINS)
        blkhist[vb * NBINS + tid] = hist[tid];
}

// ---------------- K2: exact-chunk binned matmul, kern[bin] in LDS
__global__ __launch_bounds__(256, 4) void bev_point(
    const int*   __restrict__ coords,
    const float* __restrict__ feats,    // [N,64]
    const float* __restrict__ kern,     // [16,64,128]
    const int*   __restrict__ stride_p,
    const int*   __restrict__ blkhist,  // [nblk,16]
    const int*   __restrict__ sorted,   // [16, scap]
    float*       __restrict__ f,        // [N,128]
    int*         __restrict__ head,     // [ncells] zeroed; stores pt+1
    int*         __restrict__ nxt,      // [N]; 0 = end-of-chain
    int n, int nblk, int scap)
{
    __shared__ float lk[CIN * COUT];    // 32 KB: kern[bin]
    __shared__ int sc[256];             // inclusive prefix of my bin's column
    __shared__ int tot[NBINS];
    __shared__ int cbase[NBINS + 1];    // chunk-count prefix over bins

    const int tid = threadIdx.x;

    // bin totals (LDS atomics over blkhist, ~10KB from L2)
    if (tid < NBINS) tot[tid] = 0;
    __syncthreads();
    if (tid < nblk) {
#pragma unroll
        for (int k = 0; k < NBINS; ++k)
            atomicAdd(&tot[k], blkhist[tid * NBINS + k]);
    }
    __syncthreads();
    if (tid == 0) {
        int acc = 0;
        cbase[0] = 0;
        for (int k = 0; k < NBINS; ++k) {
            acc += (tot[k] + PTS_PER_BLOCK - 1) / PTS_PER_BLOCK;
            cbase[k + 1] = acc;
        }
    }
    __syncthreads();

    const int c = blockIdx.x;
    if (c >= cbase[NBINS]) return;            // block-uniform: safe

    int bin = 0;
    while (cbase[bin + 1] <= c) ++bin;        // uniform 16-entry scan
    const int chunk = c - cbase[bin];
    const int cnt   = tot[bin];

    // inclusive prefix over my bin's per-block counts (Hillis-Steele, 256)
    {
        int v = (tid < nblk) ? blkhist[tid * NBINS + bin] : 0;
        sc[tid] = v;
        __syncthreads();
        for (int off = 1; off < 256; off <<= 1) {
            const int add = (tid >= off) ? sc[tid - off] : 0;
            __syncthreads();
            sc[tid] += add;
            __syncthreads();
        }
    }

    // stage kern[bin] -> LDS (256 thr x 8 float4)
    {
        const float4* src = (const float4*)(kern + (size_t)bin * CIN * COUT);
        float4* dst = (float4*)lk;
#pragma unroll
        for (int j = 0; j < 8; ++j)
            dst[j * 256 + tid] = src[j * 256 + tid];
    }
    __syncthreads();

    const int wave = tid >> 6;
    const int lane = tid & 63;
    const int r0 = chunk * PTS_PER_BLOCK + wave * PTS_PER_WAVE;
    const int navail = cnt - r0;
    if (navail <= 0) return;                  // no barrier after this point
    const int np = navail < PTS_PER_WAVE ? navail : PTS_PER_WAVE;

    int pts[PTS_PER_WAVE];
#pragma unroll
    for (int p = 0; p < PTS_PER_WAVE; ++p) {
        const int rr = (p < np) ? (r0 + p) : r0;   // pad tail with p0 (discarded)
        // rank -> (vb, local) via binary search on inclusive prefix (uniform)
        int lo = 0, hi = nblk;
        while (lo < hi) {
            const int mid = (lo + hi) >> 1;
            if (sc[mid] > rr) hi = mid; else lo = mid + 1;
        }
        const int local = rr - (lo ? sc[lo - 1] : 0);
        pts[p] = __builtin_amdgcn_readfirstlane(sorted[bin * scap + lo * 256 + local]);
    }

    float ax[PTS_PER_WAVE], ay[PTS_PER_WAVE];
#pragma unroll
    for (int p = 0; p < PTS_PER_WAVE; ++p) { ax[p] = 0.f; ay[p] = 0.f; }

#pragma unroll
    for (int cc = 0; cc < CIN; ++cc) {
        const float2 kv = *(const float2*)&lk[cc * COUT + 2 * lane];
#pragma unroll
        for (int p = 0; p < PTS_PER_WAVE; ++p) {
            const float fv = feats[(size_t)pts[p] * CIN + cc];  // wave-uniform -> s_load
            ax[p] = fmaf(fv, kv.x, ax[p]);
            ay[p] = fmaf(fv, kv.y, ay[p]);
        }
    }

#pragma unroll
    for (int p = 0; p < PTS_PER_WAVE; ++p) {
        if (p < np)
            *(float2*)(f + (size_t)pts[p] * COUT + 2 * lane) = make_float2(ax[p], ay[p]);
    }

    if (lane == 0) {
        const int stride = stride_p[0];
        for (int p = 0; p < np; ++p) {
            const int pt = pts[p];
            const int cx = coords[pt * 4 + 0];
            const int cz = coords[pt * 4 + 2];
            const int cb = coords[pt * 4 + 3];
            const int cell = (cb << 18) + ((cx / stride) << 9) + (cz / stride);
            const int old = atomicExch(&head[cell], pt + 1);   // lock-free push
            nxt[pt] = old;                                     // 0 = end
        }
    }
}

// ---------------- K3: wave-per-row dense output, chain-fold inlined
__global__ __launch_bounds__(256) void bev_dense_row(
    const float* __restrict__ f,        // [N,128]
    const int*   __restrict__ head,     // [ncells], pt+1 or 0
    const int*   __restrict__ nxt,      // [N]; 0 = end
    float*       __restrict__ out,      // [B,128,512,512]
    int nrows)                          // B*COUT*BEVH
{
    const int wave = threadIdx.x >> 6;
    const int lane = threadIdx.x & 63;
    const int row = blockIdx.x * 4 + wave;      // row = (b<<16)|(o<<9)|x
    if (row >= nrows) return;

    const int x = row & 511;
    const int o = (row >> 9) & 127;             // wave-uniform
    const int b = row >> 16;                    // wave-uniform
    const int* hrow = head + (b << 18) + (x << 9);   // 2KB contiguous head row
    float* const orow = out + (size_t)row * 512;

#pragma unroll
    for (int h = 0; h < 2; ++h) {
        const int z = h * 256 + lane * 4;
        const int4 h4 = *(const int4*)(hrow + z);    // coalesced 1KB/wave
        float4 v = make_float4(0.f, 0.f, 0.f, 0.f);
        int p0 = h4.x, p1 = h4.y, p2 = h4.z, p3 = h4.w;
        // level 1: owner f-loads and nxt-loads all independent (8 in flight)
        if (p0) { v.x = f[(size_t)(p0 - 1) * COUT + o]; p0 = nxt[p0 - 1]; }
        if (p1) { v.y = f[(size_t)(p1 - 1) * COUT + o]; p1 = nxt[p1 - 1]; }
        if (p2) { v.z = f[(size_t)(p2 - 1) * COUT + o]; p2 = nxt[p2 - 1]; }
        if (p3) { v.w = f[(size_t)(p3 - 1) * COUT + o]; p3 = nxt[p3 - 1]; }
        // rare collision chains (~4% of occupied cells), exec-masked
        while (p0 | p1 | p2 | p3) {
            if (p0) { v.x += f[(size_t)(p0 - 1) * COUT + o]; p0 = nxt[p0 - 1]; }
            if (p1) { v.y += f[(size_t)(p1 - 1) * COUT + o]; p1 = nxt[p1 - 1]; }
            if (p2) { v.z += f[(size_t)(p2 - 1) * COUT + o]; p2 = nxt[p2 - 1]; }
            if (p3) { v.w += f[(size_t)(p3 - 1) * COUT + o]; p3 = nxt[p3 - 1]; }
        }
        *(float4*)(orow + z) = v;                    // coalesced 1KB/wave store
    }
}

// ------------------------------------------------------------------- launch
extern "C" void kernel_launch(void* const* d_in, const int* in_sizes, int n_in,
                              void* d_out, int out_size, void* d_ws, size_t ws_size,
                              hipStream_t stream) {
    const int*   coords   = (const int*)d_in[0];
    const float* feats    = (const float*)d_in[1];
    const float* kern     = (const float*)d_in[2];
    const int*   stride_p = (const int*)d_in[3];
    float* out = (float*)d_out;

    const int n      = in_sizes[0] / 4;      // coords is [N,4]
    const int ncells = out_size / COUT;      // B*H*W = 524288
    const int nblk   = (n + 255) / 256;      // sort blocks (157; must be <=256)
    const int scap   = nblk * 256;           // per-bin segment capacity

    // Workspace: f | head | nxt | blkhist | sorted   (nothing needs memset)
    size_t off = 0;
    float* f      = (float*)((char*)d_ws + off); off += (size_t)n * COUT * sizeof(float);
    int* head     = (int*)((char*)d_ws + off);   off += (size_t)ncells * sizeof(int);
    int* nxt      = (int*)((char*)d_ws + off);   off += (size_t)n * sizeof(int);
    int* blkhist  = (int*)((char*)d_ws + off);   off += (size_t)nblk * NBINS * sizeof(int);
    int* sorted   = (int*)((char*)d_ws + off);   off += (size_t)NBINS * scap * sizeof(int);

    // K1: zero head + bucket (head zeroing ordered before K2 by dispatch order)
    bev_sort<<<nblk, 256, 0, stream>>>(coords, stride_p, head, blkhist, sorted,
                                       n, nblk, scap, ncells);

    // K2: exact chunk count (worst case: every bin has a remainder chunk)
    const int max_chunks = (n + PTS_PER_BLOCK - 1) / PTS_PER_BLOCK + NBINS;
    bev_point<<<max_chunks, 256, 0, stream>>>(coords, feats, kern, stride_p,
                                              blkhist, sorted, f, head, nxt,
                                              n, nblk, scap);

    // K3: dense output with inline chain-fold
    const int nrows = out_size / 512;        // B*COUT*BEVH = 131072
    bev_dense_row<<<nrows / 4, 256, 0, stream>>>(f, head, nxt, out, nrows);
}

// Round 3
// 445.080 us; speedup vs baseline: 3.4326x; 1.0131x over previous
//
#include <hip/hip_runtime.h>

// ToDenseBEVConvolution R14 — A/B decomposition of R13's +100us regression.
// R13 changed {sort/memset-fold, point-prologue, dense-inline-chain-walk} at
// once and regressed 351->451. Primary theory: the data-dependent while-loop
// in dense serialized scattered-load round-trips (loop exit depends on nxt
// loads -> vmcnt drain per level) and knocked dense off its 43us fill-rate
// floor. R14 keeps the proven-correct R13 sort/point (memset node stays
// deleted) but restores R11's branch-free D4 (accum) + D5 (dense) verbatim.
// 4 dispatches: sort(+zero head), point, accum, dense.
//  K1 bev_sort:  zeroes head inline; deterministic per-block histograms
//                (blkhist) + block-segmented sorted layout (no global atomic,
//                nothing needs memset).
//  K2 bev_point: exact-chunk grid (~1266); block rebuilds bin totals + prefix
//                from blkhist in LDS, binary-searches its 8 ranks, then R11's
//                LDS-kernel matmul + chain push (head=pt+1, nxt[pt]=old).
//  K3 bev_accum: R11 D4 verbatim — owner folds collision chain in-place.
//  K4 bev_dense_row: R11 D5 verbatim — branch-free, int4 head row, float4
//                stores, one scattered f-load level, fill-rate.
// NOTE: assumes nblk=(N+255)/256 <= 256 (N <= 65536; harness N=40000).

#define CIN    64
#define COUT   128
#define BEVH   512
#define BEVW   512
#define HW     (BEVH * BEVW)     // 2^18
#define NBINS  16
#define PTS_PER_WAVE  8
#define PTS_PER_BLOCK 32

// ---------------- K1: zero head + deterministic per-block bucket
__global__ __launch_bounds__(256) void bev_sort(
    const int* __restrict__ coords,   // [N,4]
    const int* __restrict__ stride_p,
    int*       __restrict__ head,     // [ncells] -> zeroed here
    int*       __restrict__ blkhist,  // [nblk,16]
    int*       __restrict__ sorted,   // [16, nblk*256] block-segmented
    int n, int nblk, int scap, int ncells)
{
    __shared__ int hist[NBINS];
    const int tid = threadIdx.x;
    const int vb  = blockIdx.x;

    // zero head (2MB over nblk*256 threads, int4 grid-stride)
    {
        int4* h4 = (int4*)head;
        const int tot4 = ncells >> 2;
        const int zero_stride = nblk * 256;
        for (int i = vb * 256 + tid; i < tot4; i += zero_stride)
            h4[i] = make_int4(0, 0, 0, 0);
    }

    if (tid < NBINS) hist[tid] = 0;
    __syncthreads();

    const int i = vb * 256 + tid;
    int k = 0, rank = 0;
    if (i < n) {
        k = coords[i * 4 + 1] / stride_p[0];
        rank = atomicAdd(&hist[k], 1);        // LDS atomic: block-local rank
    }
    __syncthreads();
    if (i < n)
        sorted[k * scap + vb * 256 + rank] = i;
    if (tid < NBINS)
        blkhist[vb * NBINS + tid] = hist[tid];
}

// ---------------- K2: exact-chunk binned matmul, kern[bin] in LDS
__global__ __launch_bounds__(256, 4) void bev_point(
    const int*   __restrict__ coords,
    const float* __restrict__ feats,    // [N,64]
    const float* __restrict__ kern,     // [16,64,128]
    const int*   __restrict__ stride_p,
    const int*   __restrict__ blkhist,  // [nblk,16]
    const int*   __restrict__ sorted,   // [16, scap]
    float*       __restrict__ f,        // [N,128]
    int*         __restrict__ head,     // [ncells] zeroed; stores pt+1
    int*         __restrict__ nxt,      // [N]; 0 = end-of-chain
    int n, int nblk, int scap)
{
    __shared__ float lk[CIN * COUT];    // 32 KB: kern[bin]
    __shared__ int sc[256];             // inclusive prefix of my bin's column
    __shared__ int tot[NBINS];
    __shared__ int cbase[NBINS + 1];    // chunk-count prefix over bins

    const int tid = threadIdx.x;

    // bin totals (LDS atomics over blkhist, ~10KB from L2)
    if (tid < NBINS) tot[tid] = 0;
    __syncthreads();
    if (tid < nblk) {
#pragma unroll
        for (int k = 0; k < NBINS; ++k)
            atomicAdd(&tot[k], blkhist[tid * NBINS + k]);
    }
    __syncthreads();
    if (tid == 0) {
        int acc = 0;
        cbase[0] = 0;
        for (int k = 0; k < NBINS; ++k) {
            acc += (tot[k] + PTS_PER_BLOCK - 1) / PTS_PER_BLOCK;
            cbase[k + 1] = acc;
        }
    }
    __syncthreads();

    const int c = blockIdx.x;
    if (c >= cbase[NBINS]) return;            // block-uniform: safe

    int bin = 0;
    while (cbase[bin + 1] <= c) ++bin;        // uniform 16-entry scan
    const int chunk = c - cbase[bin];
    const int cnt   = tot[bin];

    // inclusive prefix over my bin's per-block counts (Hillis-Steele, 256)
    {
        int v = (tid < nblk) ? blkhist[tid * NBINS + bin] : 0;
        sc[tid] = v;
        __syncthreads();
        for (int off = 1; off < 256; off <<= 1) {
            const int add = (tid >= off) ? sc[tid - off] : 0;
            __syncthreads();
            sc[tid] += add;
            __syncthreads();
        }
    }

    // stage kern[bin] -> LDS (256 thr x 8 float4)
    {
        const float4* src = (const float4*)(kern + (size_t)bin * CIN * COUT);
        float4* dst = (float4*)lk;
#pragma unroll
        for (int j = 0; j < 8; ++j)
            dst[j * 256 + tid] = src[j * 256 + tid];
    }
    __syncthreads();

    const int wave = tid >> 6;
    const int lane = tid & 63;
    const int r0 = chunk * PTS_PER_BLOCK + wave * PTS_PER_WAVE;
    const int navail = cnt - r0;
    if (navail <= 0) return;                  // no barrier after this point
    const int np = navail < PTS_PER_WAVE ? navail : PTS_PER_WAVE;

    int pts[PTS_PER_WAVE];
#pragma unroll
    for (int p = 0; p < PTS_PER_WAVE; ++p) {
        const int rr = (p < np) ? (r0 + p) : r0;   // pad tail with p0 (discarded)
        // rank -> (vb, local) via binary search on inclusive prefix (uniform)
        int lo = 0, hi = nblk;
        while (lo < hi) {
            const int mid = (lo + hi) >> 1;
            if (sc[mid] > rr) hi = mid; else lo = mid + 1;
        }
        const int local = rr - (lo ? sc[lo - 1] : 0);
        pts[p] = __builtin_amdgcn_readfirstlane(sorted[bin * scap + lo * 256 + local]);
    }

    float ax[PTS_PER_WAVE], ay[PTS_PER_WAVE];
#pragma unroll
    for (int p = 0; p < PTS_PER_WAVE; ++p) { ax[p] = 0.f; ay[p] = 0.f; }

#pragma unroll
    for (int cc = 0; cc < CIN; ++cc) {
        const float2 kv = *(const float2*)&lk[cc * COUT + 2 * lane];
#pragma unroll
        for (int p = 0; p < PTS_PER_WAVE; ++p) {
            const float fv = feats[(size_t)pts[p] * CIN + cc];  // wave-uniform -> s_load
            ax[p] = fmaf(fv, kv.x, ax[p]);
            ay[p] = fmaf(fv, kv.y, ay[p]);
        }
    }

#pragma unroll
    for (int p = 0; p < PTS_PER_WAVE; ++p) {
        if (p < np)
            *(float2*)(f + (size_t)pts[p] * COUT + 2 * lane) = make_float2(ax[p], ay[p]);
    }

    if (lane == 0) {
        const int stride = stride_p[0];
        for (int p = 0; p < np; ++p) {
            const int pt = pts[p];
            const int cx = coords[pt * 4 + 0];
            const int cz = coords[pt * 4 + 2];
            const int cb = coords[pt * 4 + 3];
            const int cell = (cb << 18) + ((cx / stride) << 9) + (cz / stride);
            const int old = atomicExch(&head[cell], pt + 1);   // lock-free push
            nxt[pt] = old;                                     // 0 = end
        }
    }
}

// ----------------- K3: R11 D4 verbatim — owner folds chain in-place into f
__global__ __launch_bounds__(256) void bev_accum(
    const int* __restrict__ coords,
    const int* __restrict__ stride_p,
    float*     __restrict__ f,          // [N,128] (in-place)
    const int* __restrict__ head,
    const int* __restrict__ nxt,
    int n)
{
    const int wave = threadIdx.x >> 6;
    const int lane = threadIdx.x & 63;
    int pt = blockIdx.x * 4 + wave;
    if (pt >= n) return;
    pt = __builtin_amdgcn_readfirstlane(pt);

    const int nx0 = __builtin_amdgcn_readfirstlane(nxt[pt]);
    if (nx0 == 0) return;                       // singleton or tail: nothing to fold

    const int stride = stride_p[0];
    const int cx = coords[pt * 4 + 0];
    const int cz = coords[pt * 4 + 2];
    const int cb = coords[pt * 4 + 3];
    const int cell = (cb << 18) + ((cx / stride) << 9) + (cz / stride);
    if (__builtin_amdgcn_readfirstlane(head[cell]) != pt + 1) return;  // owner only

    float2 acc = *(const float2*)(f + (size_t)pt * COUT + 2 * lane);
    int p = nx0;
    while (p) {                                 // disjoint chains: no hazards
        const float2 v = *(const float2*)(f + (size_t)(p - 1) * COUT + 2 * lane);
        acc.x += v.x; acc.y += v.y;
        p = __builtin_amdgcn_readfirstlane(nxt[p - 1]);
    }
    *(float2*)(f + (size_t)pt * COUT + 2 * lane) = acc;
}

// ------------- K4: R11 D5 verbatim — branch-free wave-per-row dense output
__global__ __launch_bounds__(256) void bev_dense_row(
    const float* __restrict__ f,        // [N,128] (owner rows hold cell sums)
    const int*   __restrict__ head,     // [ncells], pt+1 or 0
    float*       __restrict__ out,      // [B,128,512,512]
    int nrows)                          // B*COUT*BEVH
{
    const int wave = threadIdx.x >> 6;
    const int lane = threadIdx.x & 63;
    const int row = blockIdx.x * 4 + wave;      // row = (b<<16)|(o<<9)|x
    if (row >= nrows) return;

    const int x = row & 511;
    const int o = (row >> 9) & 127;             // wave-uniform
    const int b = row >> 16;                    // wave-uniform
    const int* hrow = head + (b << 18) + (x << 9);   // 2KB contiguous head row
    float* const orow = out + (size_t)row * 512;

#pragma unroll
    for (int h = 0; h < 2; ++h) {
        const int z = h * 256 + lane * 4;
        const int4 h4 = *(const int4*)(hrow + z);    // coalesced 1KB/wave
        float4 v = make_float4(0.f, 0.f, 0.f, 0.f);
        if (h4.x) v.x = f[(size_t)(h4.x - 1) * COUT + o];   // one scattered
        if (h4.y) v.y = f[(size_t)(h4.y - 1) * COUT + o];   // load level,
        if (h4.z) v.z = f[(size_t)(h4.z - 1) * COUT + o];   // branch-free
        if (h4.w) v.w = f[(size_t)(h4.w - 1) * COUT + o];
        *(float4*)(orow + z) = v;                    // coalesced 1KB/wave store
    }
}

// ------------------------------------------------------------------- launch
extern "C" void kernel_launch(void* const* d_in, const int* in_sizes, int n_in,
                              void* d_out, int out_size, void* d_ws, size_t ws_size,
                              hipStream_t stream) {
    const int*   coords   = (const int*)d_in[0];
    const float* feats    = (const float*)d_in[1];
    const float* kern     = (const float*)d_in[2];
    const int*   stride_p = (const int*)d_in[3];
    float* out = (float*)d_out;

    const int n      = in_sizes[0] / 4;      // coords is [N,4]
    const int ncells = out_size / COUT;      // B*H*W = 524288
    const int nblk   = (n + 255) / 256;      // sort blocks (157; must be <=256)
    const int scap   = nblk * 256;           // per-bin segment capacity

    // Workspace: f | head | nxt | blkhist | sorted   (nothing needs memset)
    size_t off = 0;
    float* f      = (float*)((char*)d_ws + off); off += (size_t)n * COUT * sizeof(float);
    int* head     = (int*)((char*)d_ws + off);   off += (size_t)ncells * sizeof(int);
    int* nxt      = (int*)((char*)d_ws + off);   off += (size_t)n * sizeof(int);
    int* blkhist  = (int*)((char*)d_ws + off);   off += (size_t)nblk * NBINS * sizeof(int);
    int* sorted   = (int*)((char*)d_ws + off);   off += (size_t)NBINS * scap * sizeof(int);

    // K1: zero head + bucket (head zeroing ordered before K2 by dispatch order)
    bev_sort<<<nblk, 256, 0, stream>>>(coords, stride_p, head, blkhist, sorted,
                                       n, nblk, scap, ncells);

    // K2: exact chunk count (worst case: every bin has a remainder chunk)
    const int max_chunks = (n + PTS_PER_BLOCK - 1) / PTS_PER_BLOCK + NBINS;
    bev_point<<<max_chunks, 256, 0, stream>>>(coords, feats, kern, stride_p,
                                              blkhist, sorted, f, head, nxt,
                                              n, nblk, scap);

    // K3: owner folds collision chains (R11 D4)
    bev_accum<<<(n + 3) / 4, 256, 0, stream>>>(coords, stride_p, f, head, nxt, n);

    // K4: branch-free dense output (R11 D5)
    const int nrows = out_size / 512;        // B*COUT*BEVH = 131072
    bev_dense_row<<<nrows / 4, 256, 0, stream>>>(f, head, out, nrows);
}

// Round 4
// 357.846 us; speedup vs baseline: 4.2694x; 1.2438x over previous
//
#include <hip/hip_runtime.h>

// ToDenseBEVConvolution R15 — isolate R13/R14's +95us regression to K2's
// prologue LDS-atomic storm. R14 proved dense chain-walk was NOT the cost
// (451->445 restoring R11 dense). What R13/R14 share vs R11 is the K2
// prologue whose bin-total loop does 157-lane lockstep atomicAdd to the SAME
// LDS address x16 bins (2512 serialized RMWs/block x 1266 blocks ~ 40-85us).
// R15 = R14 with that reduction rewritten atomic-free ([seg][bin] partial
// sums + 16-way fold) and K2's launch_bounds min-waves clamp dropped. All
// else verbatim from R14 (proven correct twice, absmax 0.0).
// 4 dispatches: sort(+zero head), point, accum, dense.
// NOTE: assumes nblk=(N+255)/256 <= 256 (N <= 65536; harness N=40000).

#define CIN    64
#define COUT   128
#define BEVH   512
#define BEVW   512
#define HW     (BEVH * BEVW)     // 2^18
#define NBINS  16
#define PTS_PER_WAVE  8
#define PTS_PER_BLOCK 32

// ---------------- K1: zero head + deterministic per-block bucket
__global__ __launch_bounds__(256) void bev_sort(
    const int* __restrict__ coords,   // [N,4]
    const int* __restrict__ stride_p,
    int*       __restrict__ head,     // [ncells] -> zeroed here
    int*       __restrict__ blkhist,  // [nblk,16]
    int*       __restrict__ sorted,   // [16, nblk*256] block-segmented
    int n, int nblk, int scap, int ncells)
{
    __shared__ int hist[NBINS];
    const int tid = threadIdx.x;
    const int vb  = blockIdx.x;

    // zero head (2MB over nblk*256 threads, int4 grid-stride)
    {
        int4* h4 = (int4*)head;
        const int tot4 = ncells >> 2;
        const int zero_stride = nblk * 256;
        for (int i = vb * 256 + tid; i < tot4; i += zero_stride)
            h4[i] = make_int4(0, 0, 0, 0);
    }

    if (tid < NBINS) hist[tid] = 0;
    __syncthreads();

    const int i = vb * 256 + tid;
    int k = 0, rank = 0;
    if (i < n) {
        k = coords[i * 4 + 1] / stride_p[0];
        rank = atomicAdd(&hist[k], 1);        // LDS atomic: block-local rank
    }
    __syncthreads();
    if (i < n)
        sorted[k * scap + vb * 256 + rank] = i;
    if (tid < NBINS)
        blkhist[vb * NBINS + tid] = hist[tid];
}

// ---------------- K2: exact-chunk binned matmul, kern[bin] in LDS
__global__ __launch_bounds__(256) void bev_point(
    const int*   __restrict__ coords,
    const float* __restrict__ feats,    // [N,64]
    const float* __restrict__ kern,     // [16,64,128]
    const int*   __restrict__ stride_p,
    const int*   __restrict__ blkhist,  // [nblk,16]
    const int*   __restrict__ sorted,   // [16, scap]
    float*       __restrict__ f,        // [N,128]
    int*         __restrict__ head,     // [ncells] zeroed; stores pt+1
    int*         __restrict__ nxt,      // [N]; 0 = end-of-chain
    int n, int nblk, int scap)
{
    __shared__ float lk[CIN * COUT];    // 32 KB: kern[bin]
    __shared__ int psum[256];           // [seg][bin] partial sums (atomic-free)
    __shared__ int sc[256];             // inclusive prefix of my bin's column
    __shared__ int tot[NBINS];
    __shared__ int cbase[NBINS + 1];    // chunk-count prefix over bins

    const int tid = threadIdx.x;

    // bin totals WITHOUT LDS atomics: thread t sums rows [seg*per, ...) of
    // column (t&15); then 16 threads fold 16 independent partials each.
    {
        const int bin16 = tid & 15;
        const int seg   = tid >> 4;
        const int per   = (nblk + 15) >> 4;
        const int rlo   = seg * per;
        int rhi = rlo + per; if (rhi > nblk) rhi = nblk;
        int s = 0;
        for (int vb = rlo; vb < rhi; ++vb) s += blkhist[vb * NBINS + bin16];
        psum[tid] = s;
    }
    __syncthreads();
    if (tid < NBINS) {
        int s = 0;
#pragma unroll
        for (int g = 0; g < 16; ++g) s += psum[g * 16 + tid];  // independent reads
        tot[tid] = s;
    }
    __syncthreads();
    if (tid == 0) {
        int acc = 0;
        cbase[0] = 0;
        for (int k = 0; k < NBINS; ++k) {
            acc += (tot[k] + PTS_PER_BLOCK - 1) / PTS_PER_BLOCK;
            cbase[k + 1] = acc;
        }
    }
    __syncthreads();

    const int c = blockIdx.x;
    if (c >= cbase[NBINS]) return;            // block-uniform: safe

    int bin = 0;
    while (cbase[bin + 1] <= c) ++bin;        // uniform 16-entry scan
    const int chunk = c - cbase[bin];
    const int cnt   = tot[bin];

    // inclusive prefix over my bin's per-block counts (Hillis-Steele, 256)
    {
        int v = (tid < nblk) ? blkhist[tid * NBINS + bin] : 0;
        sc[tid] = v;
        __syncthreads();
        for (int off = 1; off < 256; off <<= 1) {
            const int add = (tid >= off) ? sc[tid - off] : 0;
            __syncthreads();
            sc[tid] += add;
            __syncthreads();
        }
    }

    // stage kern[bin] -> LDS (256 thr x 8 float4)
    {
        const float4* src = (const float4*)(kern + (size_t)bin * CIN * COUT);
        float4* dst = (float4*)lk;
#pragma unroll
        for (int j = 0; j < 8; ++j)
            dst[j * 256 + tid] = src[j * 256 + tid];
    }
    __syncthreads();

    const int wave = tid >> 6;
    const int lane = tid & 63;
    const int r0 = chunk * PTS_PER_BLOCK + wave * PTS_PER_WAVE;
    const int navail = cnt - r0;
    if (navail <= 0) return;                  // no barrier after this point
    const int np = navail < PTS_PER_WAVE ? navail : PTS_PER_WAVE;

    int pts[PTS_PER_WAVE];
#pragma unroll
    for (int p = 0; p < PTS_PER_WAVE; ++p) {
        const int rr = (p < np) ? (r0 + p) : r0;   // pad tail with p0 (discarded)
        // rank -> (vb, local) via binary search on inclusive prefix (uniform)
        int lo = 0, hi = nblk;
        while (lo < hi) {
            const int mid = (lo + hi) >> 1;
            if (sc[mid] > rr) hi = mid; else lo = mid + 1;
        }
        const int local = rr - (lo ? sc[lo - 1] : 0);
        pts[p] = __builtin_amdgcn_readfirstlane(sorted[bin * scap + lo * 256 + local]);
    }

    float ax[PTS_PER_WAVE], ay[PTS_PER_WAVE];
#pragma unroll
    for (int p = 0; p < PTS_PER_WAVE; ++p) { ax[p] = 0.f; ay[p] = 0.f; }

#pragma unroll
    for (int cc = 0; cc < CIN; ++cc) {
        const float2 kv = *(const float2*)&lk[cc * COUT + 2 * lane];
#pragma unroll
        for (int p = 0; p < PTS_PER_WAVE; ++p) {
            const float fv = feats[(size_t)pts[p] * CIN + cc];  // wave-uniform -> s_load
            ax[p] = fmaf(fv, kv.x, ax[p]);
            ay[p] = fmaf(fv, kv.y, ay[p]);
        }
    }

#pragma unroll
    for (int p = 0; p < PTS_PER_WAVE; ++p) {
        if (p < np)
            *(float2*)(f + (size_t)pts[p] * COUT + 2 * lane) = make_float2(ax[p], ay[p]);
    }

    if (lane == 0) {
        const int stride = stride_p[0];
        for (int p = 0; p < np; ++p) {
            const int pt = pts[p];
            const int cx = coords[pt * 4 + 0];
            const int cz = coords[pt * 4 + 2];
            const int cb = coords[pt * 4 + 3];
            const int cell = (cb << 18) + ((cx / stride) << 9) + (cz / stride);
            const int old = atomicExch(&head[cell], pt + 1);   // lock-free push
            nxt[pt] = old;                                     // 0 = end
        }
    }
}

// ----------------- K3: R11 D4 verbatim — owner folds chain in-place into f
__global__ __launch_bounds__(256) void bev_accum(
    const int* __restrict__ coords,
    const int* __restrict__ stride_p,
    float*     __restrict__ f,          // [N,128] (in-place)
    const int* __restrict__ head,
    const int* __restrict__ nxt,
    int n)
{
    const int wave = threadIdx.x >> 6;
    const int lane = threadIdx.x & 63;
    int pt = blockIdx.x * 4 + wave;
    if (pt >= n) return;
    pt = __builtin_amdgcn_readfirstlane(pt);

    const int nx0 = __builtin_amdgcn_readfirstlane(nxt[pt]);
    if (nx0 == 0) return;                       // singleton or tail: nothing to fold

    const int stride = stride_p[0];
    const int cx = coords[pt * 4 + 0];
    const int cz = coords[pt * 4 + 2];
    const int cb = coords[pt * 4 + 3];
    const int cell = (cb << 18) + ((cx / stride) << 9) + (cz / stride);
    if (__builtin_amdgcn_readfirstlane(head[cell]) != pt + 1) return;  // owner only

    float2 acc = *(const float2*)(f + (size_t)pt * COUT + 2 * lane);
    int p = nx0;
    while (p) {                                 // disjoint chains: no hazards
        const float2 v = *(const float2*)(f + (size_t)(p - 1) * COUT + 2 * lane);
        acc.x += v.x; acc.y += v.y;
        p = __builtin_amdgcn_readfirstlane(nxt[p - 1]);
    }
    *(float2*)(f + (size_t)pt * COUT + 2 * lane) = acc;
}

// ------------- K4: R11 D5 verbatim — branch-free wave-per-row dense output
__global__ __launch_bounds__(256) void bev_dense_row(
    const float* __restrict__ f,        // [N,128] (owner rows hold cell sums)
    const int*   __restrict__ head,     // [ncells], pt+1 or 0
    float*       __restrict__ out,      // [B,128,512,512]
    int nrows)                          // B*COUT*BEVH
{
    const int wave = threadIdx.x >> 6;
    const int lane = threadIdx.x & 63;
    const int row = blockIdx.x * 4 + wave;      // row = (b<<16)|(o<<9)|x
    if (row >= nrows) return;

    const int x = row & 511;
    const int o = (row >> 9) & 127;             // wave-uniform
    const int b = row >> 16;                    // wave-uniform
    const int* hrow = head + (b << 18) + (x << 9);   // 2KB contiguous head row
    float* const orow = out + (size_t)row * 512;

#pragma unroll
    for (int h = 0; h < 2; ++h) {
        const int z = h * 256 + lane * 4;
        const int4 h4 = *(const int4*)(hrow + z);    // coalesced 1KB/wave
        float4 v = make_float4(0.f, 0.f, 0.f, 0.f);
        if (h4.x) v.x = f[(size_t)(h4.x - 1) * COUT + o];   // one scattered
        if (h4.y) v.y = f[(size_t)(h4.y - 1) * COUT + o];   // load level,
        if (h4.z) v.z = f[(size_t)(h4.z - 1) * COUT + o];   // branch-free
        if (h4.w) v.w = f[(size_t)(h4.w - 1) * COUT + o];
        *(float4*)(orow + z) = v;                    // coalesced 1KB/wave store
    }
}

// ------------------------------------------------------------------- launch
extern "C" void kernel_launch(void* const* d_in, const int* in_sizes, int n_in,
                              void* d_out, int out_size, void* d_ws, size_t ws_size,
                              hipStream_t stream) {
    const int*   coords   = (const int*)d_in[0];
    const float* feats    = (const float*)d_in[1];
    const float* kern     = (const float*)d_in[2];
    const int*   stride_p = (const int*)d_in[3];
    float* out = (float*)d_out;

    const int n      = in_sizes[0] / 4;      // coords is [N,4]
    const int ncells = out_size / COUT;      // B*H*W = 524288
    const int nblk   = (n + 255) / 256;      // sort blocks (157; must be <=256)
    const int scap   = nblk * 256;           // per-bin segment capacity

    // Workspace: f | head | nxt | blkhist | sorted   (nothing needs memset)
    size_t off = 0;
    float* f      = (float*)((char*)d_ws + off); off += (size_t)n * COUT * sizeof(float);
    int* head     = (int*)((char*)d_ws + off);   off += (size_t)ncells * sizeof(int);
    int* nxt      = (int*)((char*)d_ws + off);   off += (size_t)n * sizeof(int);
    int* blkhist  = (int*)((char*)d_ws + off);   off += (size_t)nblk * NBINS * sizeof(int);
    int* sorted   = (int*)((char*)d_ws + off);   off += (size_t)NBINS * scap * sizeof(int);

    // K1: zero head + bucket (head zeroing ordered before K2 by dispatch order)
    bev_sort<<<nblk, 256, 0, stream>>>(coords, stride_p, head, blkhist, sorted,
                                       n, nblk, scap, ncells);

    // K2: exact chunk count (worst case: every bin has a remainder chunk)
    const int max_chunks = (n + PTS_PER_BLOCK - 1) / PTS_PER_BLOCK + NBINS;
    bev_point<<<max_chunks, 256, 0, stream>>>(coords, feats, kern, stride_p,
                                              blkhist, sorted, f, head, nxt,
                                              n, nblk, scap);

    // K3: owner folds collision chains (R11 D4)
    bev_accum<<<(n + 3) / 4, 256, 0, stream>>>(coords, stride_p, f, head, nxt, n);

    // K4: branch-free dense output (R11 D5)
    const int nrows = out_size / 512;        // B*COUT*BEVH = 131072
    bev_dense_row<<<nrows / 4, 256, 0, stream>>>(f, head, out, nrows);
}